// Round 9
// baseline (1780.746 us; speedup 1.0000x reference)
//
#include <hip/hip_runtime.h>
#include <math.h>

// Problem constants (match reference: B,N,D,L,E,NL,H = 16,1024,128,64,32,2,4)
#define Bb 16
#define Nn 1024
#define Dd 128
#define Ll 64
#define Ee 32
#define NLn 2
#define Hh 4
#define DHh 32

#define BND (Bb * Nn * Dd)
#define BLD (Bb * Ll * Dd)
#define BED (Bb * Ee * Dd)

#define SCALE_INV_SQRT_D 0.08838834764831845f /* 1/sqrt(128) */

// ---------------------------------------------------------------------------
// Encoder kernels
// ---------------------------------------------------------------------------
__global__ void enc_obs_kernel(const float* __restrict__ x, const float* __restrict__ mask,
                               const float* __restrict__ ymask, const float* __restrict__ w,
                               const float* __restrict__ bias, float* __restrict__ obs) {
    int t = blockIdx.x * 256 + threadIdx.x;
    if (t >= BND) return;
    int d = t & (Dd - 1);
    int bn = t >> 7;
    float xv = x[bn], mk = mask[bn];
    float x2 = 1.0f - mk + ymask[bn];
    float v = xv * w[d] + x2 * w[Dd + d] + bias[d];
    obs[t] = fmaxf(v, 0.0f) * mk;
}

__global__ void enc_temp_kernel(const float* __restrict__ mark, const float* __restrict__ w,
                                const float* __restrict__ bias, float* __restrict__ th) {
    int t = blockIdx.x * 256 + threadIdx.x;
    if (t >= BLD) return;
    int d = t & (Dd - 1);
    int bl = t >> 7;
    th[t] = sinf(mark[bl] * w[d] + bias[d]);
}

__global__ void enc_var_kernel(const float* __restrict__ vw, float* __restrict__ vh) {
    int t = blockIdx.x * 256 + threadIdx.x;
    if (t >= BED) return;
    int ed = t % (Ee * Dd);
    vh[t] = fmaxf(vw[ed], 0.0f);
}

// ---------------------------------------------------------------------------
// Batched GEMM, optionally dual-output: C[b,m,:] = X[b,m,:] @ W + bias and
// (DUAL) C2[b,m,:] = X[b,m,:] @ W2 + bias2 — X (gather/concat) staged ONCE.
// 32-row tiles. epi (single only): 0 none; 1 resid+relu; 2 relu(resid+relu).
// ---------------------------------------------------------------------------
template <bool DUAL>
__global__ __launch_bounds__(256) void gemm_kernel(
    const float* __restrict__ X0, const int* __restrict__ I0, int R0,
    const float* __restrict__ X1, const int* __restrict__ I1, int R1,
    const float* __restrict__ X2, const int* __restrict__ I2, int R2,
    const float* __restrict__ W, const float* __restrict__ bias,
    const float* __restrict__ W2, const float* __restrict__ bias2,
    const float* __restrict__ resid, float* __restrict__ C, float* __restrict__ C2,
    int M, int K, int epi) {
    __shared__ float Xs[32][36];    // 32 rows x 32 cols
    __shared__ float Ws[32][132];   // 32 k-rows x 128 cols
    __shared__ float Ws2[DUAL ? 32 : 1][DUAL ? 132 : 1];

    int b = blockIdx.z;
    int row0 = blockIdx.x * 32;
    int tid = threadIdx.x;
    int tx = tid & 31, ty = tid >> 5;

    float acc[4][4], acc2[4][4];
#pragma unroll
    for (int r = 0; r < 4; ++r)
#pragma unroll
        for (int c = 0; c < 4; ++c) { acc[r][c] = 0.0f; acc2[r][c] = 0.0f; }

    int nchunk = K >> 5;
    for (int ch = 0; ch < nchunk; ++ch) {
        int kc = ch << 5;
        const float* Xp;
        const int* Ip;
        int Rs;
        int sel = kc >> 7;
        if (sel == 0) { Xp = X0; Ip = I0; Rs = R0; }
        else if (sel == 1) { Xp = X1; Ip = I1; Rs = R1; }
        else { Xp = X2; Ip = I2; Rs = R2; }
        int col0 = kc & (Dd - 1);

        __syncthreads();
        {   // stage X tile: 32 rows x 32 cols (one float4 per thread)
            int lr = tid >> 3, cq = tid & 7;
            int gm = row0 + lr;
            float4 a0 = make_float4(0.f, 0.f, 0.f, 0.f);
            if (gm < M) {
                int rr = Ip ? Ip[(size_t)b * M + gm] : gm;
                a0 = *(const float4*)(Xp + ((size_t)b * Rs + rr) * Dd + col0 + cq * 4);
            }
            *(float4*)&Xs[lr][cq * 4] = a0;
        }
        {   // stage W (and W2) tiles: 32 rows x 128 cols each
            int kr = tid >> 5, c = (tid & 31) * 4;
#pragma unroll
            for (int i = 0; i < 4; ++i) {
                int krow = kr + i * 8;
                *(float4*)&Ws[krow][c] = *(const float4*)&W[(size_t)(kc + krow) * Dd + c];
                if (DUAL)
                    *(float4*)&Ws2[krow][c] = *(const float4*)&W2[(size_t)(kc + krow) * Dd + c];
            }
        }
        __syncthreads();

#pragma unroll
        for (int k4 = 0; k4 < 8; ++k4) {
            float4 w0 = *(const float4*)&Ws[k4 * 4 + 0][tx * 4];
            float4 w1 = *(const float4*)&Ws[k4 * 4 + 1][tx * 4];
            float4 w2 = *(const float4*)&Ws[k4 * 4 + 2][tx * 4];
            float4 w3 = *(const float4*)&Ws[k4 * 4 + 3][tx * 4];
            float4 u0, u1, u2, u3;
            if (DUAL) {
                u0 = *(const float4*)&Ws2[k4 * 4 + 0][tx * 4];
                u1 = *(const float4*)&Ws2[k4 * 4 + 1][tx * 4];
                u2 = *(const float4*)&Ws2[k4 * 4 + 2][tx * 4];
                u3 = *(const float4*)&Ws2[k4 * 4 + 3][tx * 4];
            }
#pragma unroll
            for (int rr = 0; rr < 4; ++rr) {
                float4 xv = *(const float4*)&Xs[ty * 4 + rr][k4 * 4];
                acc[rr][0] += xv.x * w0.x + xv.y * w1.x + xv.z * w2.x + xv.w * w3.x;
                acc[rr][1] += xv.x * w0.y + xv.y * w1.y + xv.z * w2.y + xv.w * w3.y;
                acc[rr][2] += xv.x * w0.z + xv.y * w1.z + xv.z * w2.z + xv.w * w3.z;
                acc[rr][3] += xv.x * w0.w + xv.y * w1.w + xv.z * w2.w + xv.w * w3.w;
                if (DUAL) {
                    acc2[rr][0] += xv.x * u0.x + xv.y * u1.x + xv.z * u2.x + xv.w * u3.x;
                    acc2[rr][1] += xv.x * u0.y + xv.y * u1.y + xv.z * u2.y + xv.w * u3.y;
                    acc2[rr][2] += xv.x * u0.z + xv.y * u1.z + xv.z * u2.z + xv.w * u3.z;
                    acc2[rr][3] += xv.x * u0.w + xv.y * u1.w + xv.z * u2.w + xv.w * u3.w;
                }
            }
        }
    }

    float4 bv = *(const float4*)&bias[tx * 4];
    float4 bv2 = make_float4(0.f, 0.f, 0.f, 0.f);
    if (DUAL) bv2 = *(const float4*)&bias2[tx * 4];
#pragma unroll
    for (int rr = 0; rr < 4; ++rr) {
        int gm = row0 + ty * 4 + rr;
        if (gm >= M) continue;
        size_t base = ((size_t)b * M + gm) * Dd + tx * 4;
        float4 o;
        o.x = acc[rr][0] + bv.x;
        o.y = acc[rr][1] + bv.y;
        o.z = acc[rr][2] + bv.z;
        o.w = acc[rr][3] + bv.w;
        if (!DUAL && epi >= 1) {
            float4 r4 = *(const float4*)&resid[base];
            o.x = r4.x + fmaxf(o.x, 0.f);
            o.y = r4.y + fmaxf(o.y, 0.f);
            o.z = r4.z + fmaxf(o.z, 0.f);
            o.w = r4.w + fmaxf(o.w, 0.f);
            if (epi == 2) {
                o.x = fmaxf(o.x, 0.f);
                o.y = fmaxf(o.y, 0.f);
                o.z = fmaxf(o.z, 0.f);
                o.w = fmaxf(o.w, 0.f);
            }
        }
        *(float4*)&C[base] = o;
        if (DUAL) {
            float4 o2;
            o2.x = acc2[rr][0] + bv2.x;
            o2.y = acc2[rr][1] + bv2.y;
            o2.z = acc2[rr][2] + bv2.z;
            o2.w = acc2[rr][3] + bv2.w;
            *(float4*)&C2[base] = o2;
        }
    }
}

// ---------------------------------------------------------------------------
// Flash attention, distributed accumulator (round-6 proven version).
//   grid = (M/32, Hh, Bb), block = 256 (4 waves), 8 queries per wave.
//   Phase S (lane = key); phase AV (lane = (key-half, dim)); acc = 1 VGPR/query.
//   K/V staged transposed [32][65]; kreg/vreg reused across 8 queries.
// MODE 0: incidence mask (idx[b,k]==m && mask), wave-level chunk skip.
// MODE 1: nmask (mask[b,m] && mask[b,k]).
// ---------------------------------------------------------------------------
template <int MODE>
__global__ __launch_bounds__(256, 2) void attn_flash2_kernel(
    const float* __restrict__ Q, const float* __restrict__ Kp, const float* __restrict__ Vp,
    const int* __restrict__ idxp, const float* __restrict__ maskp,
    float* __restrict__ O, int M) {
    __shared__ float Kt[32][65];  // Kt[d][k]
    __shared__ float Vt[32][65];  // Vt[d][k]
    __shared__ float Qs[32][36];
    __shared__ float Ps[4][64];

    int b = blockIdx.z, h = blockIdx.y;
    int tid = threadIdx.x;
    int lane = tid & 63, wid = tid >> 6;
    int mblk = blockIdx.x * 32;
    int m0 = mblk + wid * 8;

    int kh = lane >> 5;
    int dv = lane & 31;

    {
        int r = tid >> 3, c = tid & 7;
        float4 qv = *(const float4*)(Q + ((size_t)b * M + mblk + r) * Dd + (size_t)h * DHh + c * 4);
        *(float4*)&Qs[r][c * 4] = qv;
    }

    float acc[8], lpart[8], mrun[8];
#pragma unroll
    for (int qi = 0; qi < 8; ++qi) { acc[qi] = 0.f; lpart[qi] = 0.f; mrun[qi] = -INFINITY; }
    bool okq[8];
#pragma unroll
    for (int qi = 0; qi < 8; ++qi) okq[qi] = true;
    if (MODE == 1) {
#pragma unroll
        for (int qi = 0; qi < 8; ++qi) okq[qi] = (maskp[(size_t)b * Nn + m0 + qi] != 0.0f);
    }

    for (int n0 = 0; n0 < Nn; n0 += 64) {
        __syncthreads();
        {
            int k = tid >> 2, q4 = tid & 3;
            size_t gk = ((size_t)b * Nn + n0 + k) * Dd + (size_t)h * DHh;
            const float4* kp = (const float4*)(Kp + gk) + q4 * 2;
            const float4* vp = (const float4*)(Vp + gk) + q4 * 2;
            float4 k0 = kp[0], k1 = kp[1];
            float4 v0 = vp[0], v1 = vp[1];
            int d0 = q4 * 8;
            Kt[d0 + 0][k] = k0.x; Kt[d0 + 1][k] = k0.y; Kt[d0 + 2][k] = k0.z; Kt[d0 + 3][k] = k0.w;
            Kt[d0 + 4][k] = k1.x; Kt[d0 + 5][k] = k1.y; Kt[d0 + 6][k] = k1.z; Kt[d0 + 7][k] = k1.w;
            Vt[d0 + 0][k] = v0.x; Vt[d0 + 1][k] = v0.y; Vt[d0 + 2][k] = v0.z; Vt[d0 + 3][k] = v0.w;
            Vt[d0 + 4][k] = v1.x; Vt[d0 + 5][k] = v1.y; Vt[d0 + 6][k] = v1.z; Vt[d0 + 7][k] = v1.w;
        }
        float km = maskp[(size_t)b * Nn + n0 + lane];
        bool kok = (km != 0.0f);
        int tag = 0;
        if (MODE == 0) tag = idxp[(size_t)b * Nn + n0 + lane];
        __syncthreads();

        if (MODE == 0) {
            bool anyUse = __any(kok && (unsigned)(tag - m0) < 8u);
            float minm = fminf(fminf(fminf(mrun[0], mrun[1]), fminf(mrun[2], mrun[3])),
                               fminf(fminf(mrun[4], mrun[5]), fminf(mrun[6], mrun[7])));
            if (!anyUse && minm > -5e9f) continue;
        }

        float kreg[32], vreg[32];
#pragma unroll
        for (int j = 0; j < 32; ++j) kreg[j] = Kt[j][lane];
#pragma unroll
        for (int j = 0; j < 32; ++j) vreg[j] = Vt[dv][kh * 32 + j];

#pragma unroll
        for (int qi = 0; qi < 8; ++qi) {
            bool ok = (MODE == 0) ? (kok && tag == m0 + qi) : (okq[qi] && kok);
            if (!__any(ok) && mrun[qi] > -5e9f) continue;

            const float4* qrow = (const float4*)&Qs[wid * 8 + qi][0];
            float s0 = 0.f, s1 = 0.f, s2 = 0.f, s3 = 0.f;
#pragma unroll
            for (int j4 = 0; j4 < 8; ++j4) {
                float4 qv = qrow[j4];
                s0 += qv.x * kreg[j4 * 4 + 0];
                s1 += qv.y * kreg[j4 * 4 + 1];
                s2 += qv.z * kreg[j4 * 4 + 2];
                s3 += qv.w * kreg[j4 * 4 + 3];
            }
            float s = (s0 + s1) + (s2 + s3);
            s = ok ? s * SCALE_INV_SQRT_D : -1e10f;

            float cmax = s;
#pragma unroll
            for (int off = 32; off >= 1; off >>= 1)
                cmax = fmaxf(cmax, __shfl_xor(cmax, off, 64));

            if (cmax > mrun[qi]) {
                float corr = __expf(mrun[qi] - cmax);
                lpart[qi] *= corr;
                acc[qi] *= corr;
                mrun[qi] = cmax;
            }
            float p = __expf(s - mrun[qi]);
            lpart[qi] += p;
            Ps[wid][lane] = p;

            float a = acc[qi];
#pragma unroll
            for (int j4 = 0; j4 < 8; ++j4) {
                float4 pv = *(const float4*)&Ps[wid][kh * 32 + j4 * 4];
                a += pv.x * vreg[j4 * 4 + 0];
                a += pv.y * vreg[j4 * 4 + 1];
                a += pv.z * vreg[j4 * 4 + 2];
                a += pv.w * vreg[j4 * 4 + 3];
            }
            acc[qi] = a;
        }
    }

#pragma unroll
    for (int qi = 0; qi < 8; ++qi) {
        float l = lpart[qi];
#pragma unroll
        for (int off = 32; off >= 1; off >>= 1) l += __shfl_xor(l, off, 64);
        float a = acc[qi] + __shfl_xor(acc[qi], 32, 64);
        float inv = 1.0f / l;
        if (lane < 32) {
            int r = wid * 8 + qi;
            float qd = Qs[r][lane];
            O[((size_t)b * M + mblk + r) * Dd + (size_t)h * DHh + lane] = qd + a * inv;
        }
    }
}

// ---------------------------------------------------------------------------
// IAA (hyperedge2hyperedge): tiny single-head attention over E=32.
// ---------------------------------------------------------------------------
__global__ void iaa_scores_kernel(const float* __restrict__ q, const float* __restrict__ k,
                                  float* __restrict__ s) {
    int t = blockIdx.x * 256 + threadIdx.x;
    if (t >= Bb * Ee * Ee) return;
    int j = t & (Ee - 1);
    int i = (t >> 5) & (Ee - 1);
    int b = t >> 10;
    const float4* qp = (const float4*)(q + ((size_t)b * Ee + i) * Dd);
    const float4* kp = (const float4*)(k + ((size_t)b * Ee + j) * Dd);
    float acc = 0.0f;
#pragma unroll
    for (int d = 0; d < 32; ++d) {
        float4 a = qp[d], c = kp[d];
        acc += a.x * c.x + a.y * c.y + a.z * c.z + a.w * c.w;
    }
    s[t] = acc * SCALE_INV_SQRT_D;
}

__global__ void iaa_softmax_kernel(float* __restrict__ s) {
    int r = blockIdx.x * 256 + threadIdx.x;
    if (r >= Bb * Ee) return;
    float* row = s + (size_t)r * Ee;
    float mx = -INFINITY;
    for (int j = 0; j < Ee; ++j) mx = fmaxf(mx, row[j]);
    float sum = 0.0f;
    for (int j = 0; j < Ee; ++j) sum += __expf(row[j] - mx);
    float inv = 1.0f / sum;
    for (int j = 0; j < Ee; ++j) row[j] = __expf(row[j] - mx) * inv;
}

__global__ void iaa_av_kernel(const float* __restrict__ s, const float* __restrict__ v,
                              float* __restrict__ o) {
    int t = blockIdx.x * 256 + threadIdx.x;
    if (t >= Bb * Ee * Dd) return;
    int d = t & (Dd - 1);
    int i = (t >> 7) & (Ee - 1);
    int b = t >> 12;
    const float* sr = s + ((size_t)b * Ee + i) * Ee;
    float acc = 0.0f;
#pragma unroll
    for (int j = 0; j < Ee; ++j) acc += sr[j] * v[((size_t)b * Ee + j) * Dd + d];
    o[t] = acc;
}

// ---------------------------------------------------------------------------
// Host-side orchestration
// ---------------------------------------------------------------------------
static inline void launch_gemm(hipStream_t st, const float* X0, const int* I0, int R0,
                               const float* X1, const int* I1, int R1, const float* X2,
                               const int* I2, int R2, const float* W, const float* bias,
                               const float* resid, float* C, int M, int K, int epi) {
    dim3 g((M + 31) / 32, 1, Bb);
    gemm_kernel<false><<<g, 256, 0, st>>>(X0, I0, R0, X1, I1, R1, X2, I2, R2, W, bias,
                                          nullptr, nullptr, resid, C, nullptr, M, K, epi);
}

static inline void launch_gemm_dual(hipStream_t st, const float* X0, const int* I0, int R0,
                                    const float* X1, const int* I1, int R1, const float* X2,
                                    const int* I2, int R2, const float* W, const float* bias,
                                    const float* W2, const float* bias2, float* C, float* C2,
                                    int M, int K) {
    dim3 g((M + 31) / 32, 1, Bb);
    gemm_kernel<true><<<g, 256, 0, st>>>(X0, I0, R0, X1, I1, R1, X2, I2, R2, W, bias, W2, bias2,
                                         nullptr, C, C2, M, K, 0);
}

static inline void launch_attn_inc(hipStream_t st, const float* Q, const float* K, const float* V,
                                   const int* idxp, const float* maskp, float* O, int M) {
    dim3 g(M / 32, Hh, Bb);
    attn_flash2_kernel<0><<<g, 256, 0, st>>>(Q, K, V, idxp, maskp, O, M);
}

static inline void launch_attn_obs(hipStream_t st, const float* Q, const float* K, const float* V,
                                   const float* maskp, float* O) {
    dim3 g(Nn / 32, Hh, Bb);
    attn_flash2_kernel<1><<<g, 256, 0, st>>>(Q, K, V, nullptr, maskp, O, Nn);
}

extern "C" void kernel_launch(void* const* d_in, const int* in_sizes, int n_in, void* d_out,
                              int out_size, void* d_ws, size_t ws_size, hipStream_t stream) {
    const float* x = (const float*)d_in[0];
    const float* mask = (const float*)d_in[1];
    const float* ymask = (const float*)d_in[2];
    const float* mark = (const float*)d_in[3];
    const float* w_obs = (const float*)d_in[4];
    const float* b_obs = (const float*)d_in[5];
    const float* w_tm = (const float*)d_in[6];
    const float* b_tm = (const float*)d_in[7];
    const float* var_w = (const float*)d_in[8];
    const float* tq_w = (const float*)d_in[9];
    const float* tq_b = (const float*)d_in[10];
    const float* tk_w = (const float*)d_in[11];
    const float* tk_b = (const float*)d_in[12];
    const float* tv_w = (const float*)d_in[13];
    const float* tv_b = (const float*)d_in[14];
    const float* to_w = (const float*)d_in[15];
    const float* to_b = (const float*)d_in[16];
    const float* vq_w = (const float*)d_in[17];
    const float* vq_b = (const float*)d_in[18];
    const float* vk_w = (const float*)d_in[19];
    const float* vk_b = (const float*)d_in[20];
    const float* vv_w = (const float*)d_in[21];
    const float* vv_b = (const float*)d_in[22];
    const float* vo_w = (const float*)d_in[23];
    const float* vo_b = (const float*)d_in[24];
    const float* sq_w = (const float*)d_in[25];
    const float* sq_b = (const float*)d_in[26];
    const float* sk_w = (const float*)d_in[27];
    const float* sk_b = (const float*)d_in[28];
    const float* sv_w = (const float*)d_in[29];
    const float* sv_b = (const float*)d_in[30];
    const float* so_w = (const float*)d_in[31];
    const float* so_b = (const float*)d_in[32];
    const float* iq_w = (const float*)d_in[33];
    const float* iq_b = (const float*)d_in[34];
    const float* ik_w = (const float*)d_in[35];
    const float* ik_b = (const float*)d_in[36];
    const float* iv_w = (const float*)d_in[37];
    const float* iv_b = (const float*)d_in[38];
    const int* vidx = (const int*)d_in[39];
    const int* tidx = (const int*)d_in[40];

    float* out = (float*)d_out;
    float* out_obs = out;
    float* out_temp = out + BND;
    float* out_var = out + BND + BLD;

    float* ws = (float*)d_ws;
    float* obs_a = ws;
    float* obs_b = obs_a + BND;
    float* qb = obs_b + BND;
    float* kb = qb + BND;
    float* vb = kb + BND;
    float* attno = vb + BND;
    float* temp_a = attno + BND;
    float* temp_b = temp_a + BLD;
    float* var_a = temp_b + BLD;
    float* var_b = var_a + BED;
    float* sbuf = var_b + BED;  // B*E*E

    enc_obs_kernel<<<(BND + 255) / 256, 256, 0, stream>>>(x, mask, ymask, w_obs, b_obs, obs_a);
    enc_temp_kernel<<<(BLD + 255) / 256, 256, 0, stream>>>(mark, w_tm, b_tm, temp_a);
    enc_var_kernel<<<(BED + 255) / 256, 256, 0, stream>>>(var_w, var_a);

    float* t_old = temp_a;
    float* v_old = var_a;
    float* o_old = obs_a;

    for (int i = 0; i < NLn; ++i) {
        int last = (i == NLn - 1);
        float* t_new = last ? out_temp : temp_b;
        float* v_new = (v_old == var_a) ? var_b : var_a;
        float* o_new = last ? out_obs : obs_b;

        const float* tqW = tq_w + (size_t)i * Dd * Dd;
        const float* tkW = tk_w + (size_t)i * 2 * Dd * Dd;
        const float* tvW = tv_w + (size_t)i * 2 * Dd * Dd;
        const float* toW = to_w + (size_t)i * Dd * Dd;
        const float* vqW = vq_w + (size_t)i * Dd * Dd;
        const float* vkW = vk_w + (size_t)i * 2 * Dd * Dd;
        const float* vvW = vv_w + (size_t)i * 2 * Dd * Dd;
        const float* voW = vo_w + (size_t)i * Dd * Dd;
        const float* sqW = sq_w + (size_t)i * Dd * Dd;
        const float* skW = sk_w + (size_t)i * 3 * Dd * Dd;
        const float* svW = sv_w + (size_t)i * 3 * Dd * Dd;
        const float* soW = so_w + (size_t)i * Dd * Dd;

        // ---- temporal MAB: Q=temp_he(old), K=[var_g(old), obs] ----
        launch_gemm(stream, t_old, nullptr, Ll, nullptr, nullptr, 0, nullptr, nullptr, 0, tqW,
                    tq_b + i * Dd, nullptr, qb, Ll, Dd, 0);
        launch_gemm_dual(stream, v_old, vidx, Ee, o_old, nullptr, Nn, nullptr, nullptr, 0,
                         tkW, tk_b + i * Dd, tvW, tv_b + i * Dd, kb, vb, Nn, 2 * Dd);
        launch_attn_inc(stream, qb, kb, vb, tidx, mask, attno, Ll);
        launch_gemm(stream, attno, nullptr, Ll, nullptr, nullptr, 0, nullptr, nullptr, 0, toW,
                    to_b + i * Dd, attno, t_new, Ll, Dd, 1);

        // ---- variable MAB: Q=var_he(old), K=[temp_g(old), obs] ----
        launch_gemm(stream, v_old, nullptr, Ee, nullptr, nullptr, 0, nullptr, nullptr, 0, vqW,
                    vq_b + i * Dd, nullptr, qb, Ee, Dd, 0);
        launch_gemm_dual(stream, t_old, tidx, Ll, o_old, nullptr, Nn, nullptr, nullptr, 0,
                         vkW, vk_b + i * Dd, vvW, vv_b + i * Dd, kb, vb, Nn, 2 * Dd);
        launch_attn_inc(stream, qb, kb, vb, vidx, mask, attno, Ee);
        launch_gemm(stream, attno, nullptr, Ee, nullptr, nullptr, 0, nullptr, nullptr, 0, voW,
                    vo_b + i * Dd, attno, v_new, Ee, Dd, 1);

        // ---- obs MAB: Q=obs(old), K=[temp_g(new), var_g(new), obs(old)] ----
        launch_gemm(stream, o_old, nullptr, Nn, nullptr, nullptr, 0, nullptr, nullptr, 0, sqW,
                    sq_b + i * Dd, nullptr, qb, Nn, Dd, 0);
        launch_gemm_dual(stream, t_new, tidx, Ll, v_new, vidx, Ee, o_old, nullptr, Nn,
                         skW, sk_b + i * Dd, svW, sv_b + i * Dd, kb, vb, Nn, 3 * Dd);
        launch_attn_obs(stream, qb, kb, vb, mask, attno);
        launch_gemm(stream, attno, nullptr, Nn, nullptr, nullptr, 0, nullptr, nullptr, 0, soW,
                    so_b + i * Dd, attno, o_new, Nn, Dd, 2);

        t_old = t_new;
        v_old = v_new;
        o_old = o_new;
    }

    // ---- IAA on var_he (last layer): iq+ik merged (shared X), then iv ----
    launch_gemm_dual(stream, v_old, nullptr, Ee, nullptr, nullptr, 0, nullptr, nullptr, 0,
                     iq_w, iq_b, ik_w, ik_b, qb, kb, Ee, Dd);
    launch_gemm(stream, v_old, nullptr, Ee, nullptr, nullptr, 0, nullptr, nullptr, 0, iv_w, iv_b,
                nullptr, vb, Ee, Dd, 0);
    iaa_scores_kernel<<<(Bb * Ee * Ee + 255) / 256, 256, 0, stream>>>(qb, kb, sbuf);
    iaa_softmax_kernel<<<(Bb * Ee + 255) / 256, 256, 0, stream>>>(sbuf);
    iaa_av_kernel<<<(Bb * Ee * Dd + 255) / 256, 256, 0, stream>>>(sbuf, vb, out_var);
}

// Round 10
// 1637.049 us; speedup vs baseline: 1.0878x; 1.0878x over previous
//
#include <hip/hip_runtime.h>
#include <math.h>

// Problem constants (match reference: B,N,D,L,E,NL,H = 16,1024,128,64,32,2,4)
#define Bb 16
#define Nn 1024
#define Dd 128
#define Ll 64
#define Ee 32
#define NLn 2
#define Hh 4
#define DHh 32

#define BND (Bb * Nn * Dd)
#define BLD (Bb * Ll * Dd)
#define BED (Bb * Ee * Dd)

#define SCALE_INV_SQRT_D 0.08838834764831845f /* 1/sqrt(128) */

// ---------------------------------------------------------------------------
// Encoder kernels
// ---------------------------------------------------------------------------
__global__ void enc_obs_kernel(const float* __restrict__ x, const float* __restrict__ mask,
                               const float* __restrict__ ymask, const float* __restrict__ w,
                               const float* __restrict__ bias, float* __restrict__ obs) {
    int t = blockIdx.x * 256 + threadIdx.x;
    if (t >= BND) return;
    int d = t & (Dd - 1);
    int bn = t >> 7;
    float xv = x[bn], mk = mask[bn];
    float x2 = 1.0f - mk + ymask[bn];
    float v = xv * w[d] + x2 * w[Dd + d] + bias[d];
    obs[t] = fmaxf(v, 0.0f) * mk;
}

__global__ void enc_temp_kernel(const float* __restrict__ mark, const float* __restrict__ w,
                                const float* __restrict__ bias, float* __restrict__ th) {
    int t = blockIdx.x * 256 + threadIdx.x;
    if (t >= BLD) return;
    int d = t & (Dd - 1);
    int bl = t >> 7;
    th[t] = sinf(mark[bl] * w[d] + bias[d]);
}

__global__ void enc_var_kernel(const float* __restrict__ vw, float* __restrict__ vh) {
    int t = blockIdx.x * 256 + threadIdx.x;
    if (t >= BED) return;
    int ed = t % (Ee * Dd);
    vh[t] = fmaxf(vw[ed], 0.0f);
}

// ---------------------------------------------------------------------------
// Generic batched GEMM (round-6 proven single-output version):
// C[b,m,:] = concat-X[b,m,:] @ W + bias; 32-row tiles.
// epi: 0 = none; 1 = resid + relu(C); 2 = relu(resid + relu(C))
// ---------------------------------------------------------------------------
__global__ __launch_bounds__(256) void gemm_kernel(
    const float* __restrict__ X0, const int* __restrict__ I0, int R0,
    const float* __restrict__ X1, const int* __restrict__ I1, int R1,
    const float* __restrict__ X2, const int* __restrict__ I2, int R2,
    const float* __restrict__ W, const float* __restrict__ bias,
    const float* __restrict__ resid, float* __restrict__ C,
    int M, int K, int epi) {
    __shared__ float Xs[32][36];   // 32 rows x 32 cols, padded stride 36
    __shared__ float Ws[32][132];  // 32 k-rows x 128 cols, padded stride 132

    int b = blockIdx.z;
    int row0 = blockIdx.x * 32;
    int tid = threadIdx.x;
    int tx = tid & 31, ty = tid >> 5;

    float acc[4][4];
#pragma unroll
    for (int r = 0; r < 4; ++r)
#pragma unroll
        for (int c = 0; c < 4; ++c) acc[r][c] = 0.0f;

    int nchunk = K >> 5;
    for (int ch = 0; ch < nchunk; ++ch) {
        int kc = ch << 5;
        const float* Xp;
        const int* Ip;
        int Rs;
        int sel = kc >> 7;
        if (sel == 0) { Xp = X0; Ip = I0; Rs = R0; }
        else if (sel == 1) { Xp = X1; Ip = I1; Rs = R1; }
        else { Xp = X2; Ip = I2; Rs = R2; }
        int col0 = kc & (Dd - 1);

        __syncthreads();
        {   // stage X tile: 32 rows x 32 cols (one float4 per thread)
            int lr = tid >> 3, cq = tid & 7;
            int gm = row0 + lr;
            float4 a0 = make_float4(0.f, 0.f, 0.f, 0.f);
            if (gm < M) {
                int rr = Ip ? Ip[(size_t)b * M + gm] : gm;
                a0 = *(const float4*)(Xp + ((size_t)b * Rs + rr) * Dd + col0 + cq * 4);
            }
            *(float4*)&Xs[lr][cq * 4] = a0;
        }
        {   // stage W tile: 32 rows x 128 cols
            int kr = tid >> 5, c = (tid & 31) * 4;
#pragma unroll
            for (int i = 0; i < 4; ++i) {
                int krow = kr + i * 8;
                *(float4*)&Ws[krow][c] = *(const float4*)&W[(size_t)(kc + krow) * Dd + c];
            }
        }
        __syncthreads();

#pragma unroll
        for (int k4 = 0; k4 < 8; ++k4) {
            float4 w0 = *(const float4*)&Ws[k4 * 4 + 0][tx * 4];
            float4 w1 = *(const float4*)&Ws[k4 * 4 + 1][tx * 4];
            float4 w2 = *(const float4*)&Ws[k4 * 4 + 2][tx * 4];
            float4 w3 = *(const float4*)&Ws[k4 * 4 + 3][tx * 4];
#pragma unroll
            for (int rr = 0; rr < 4; ++rr) {
                float4 xv = *(const float4*)&Xs[ty * 4 + rr][k4 * 4];
                acc[rr][0] += xv.x * w0.x + xv.y * w1.x + xv.z * w2.x + xv.w * w3.x;
                acc[rr][1] += xv.x * w0.y + xv.y * w1.y + xv.z * w2.y + xv.w * w3.y;
                acc[rr][2] += xv.x * w0.z + xv.y * w1.z + xv.z * w2.z + xv.w * w3.z;
                acc[rr][3] += xv.x * w0.w + xv.y * w1.w + xv.z * w2.w + xv.w * w3.w;
            }
        }
    }

    float4 bv = *(const float4*)&bias[tx * 4];
#pragma unroll
    for (int rr = 0; rr < 4; ++rr) {
        int gm = row0 + ty * 4 + rr;
        if (gm >= M) continue;
        size_t base = ((size_t)b * M + gm) * Dd + tx * 4;
        float4 o;
        o.x = acc[rr][0] + bv.x;
        o.y = acc[rr][1] + bv.y;
        o.z = acc[rr][2] + bv.z;
        o.w = acc[rr][3] + bv.w;
        if (epi >= 1) {
            float4 r4 = *(const float4*)&resid[base];
            o.x = r4.x + fmaxf(o.x, 0.f);
            o.y = r4.y + fmaxf(o.y, 0.f);
            o.z = r4.z + fmaxf(o.z, 0.f);
            o.w = r4.w + fmaxf(o.w, 0.f);
            if (epi == 2) {
                o.x = fmaxf(o.x, 0.f);
                o.y = fmaxf(o.y, 0.f);
                o.z = fmaxf(o.z, 0.f);
                o.w = fmaxf(o.w, 0.f);
            }
        }
        *(float4*)&C[base] = o;
    }
}

// ---------------------------------------------------------------------------
// Incidence-masked flash attention (temporal/var): proven round-6 kernel.
// grid = (M/32, Hh, Bb), 4 waves, 8 queries/wave, 64-key chunks + skip.
// ---------------------------------------------------------------------------
__global__ __launch_bounds__(256, 2) void attn_inc_kernel(
    const float* __restrict__ Q, const float* __restrict__ Kp, const float* __restrict__ Vp,
    const int* __restrict__ idxp, const float* __restrict__ maskp,
    float* __restrict__ O, int M) {
    __shared__ float Kt[32][65];  // Kt[d][k]
    __shared__ float Vt[32][65];  // Vt[d][k]
    __shared__ float Qs[32][36];
    __shared__ float Ps[4][64];

    int b = blockIdx.z, h = blockIdx.y;
    int tid = threadIdx.x;
    int lane = tid & 63, wid = tid >> 6;
    int mblk = blockIdx.x * 32;
    int m0 = mblk + wid * 8;

    int kh = lane >> 5;
    int dv = lane & 31;

    {
        int r = tid >> 3, c = tid & 7;
        float4 qv = *(const float4*)(Q + ((size_t)b * M + mblk + r) * Dd + (size_t)h * DHh + c * 4);
        *(float4*)&Qs[r][c * 4] = qv;
    }

    float acc[8], lpart[8], mrun[8];
#pragma unroll
    for (int qi = 0; qi < 8; ++qi) { acc[qi] = 0.f; lpart[qi] = 0.f; mrun[qi] = -INFINITY; }

    for (int n0 = 0; n0 < Nn; n0 += 64) {
        __syncthreads();
        {
            int k = tid >> 2, q4 = tid & 3;
            size_t gk = ((size_t)b * Nn + n0 + k) * Dd + (size_t)h * DHh;
            const float4* kp = (const float4*)(Kp + gk) + q4 * 2;
            const float4* vp = (const float4*)(Vp + gk) + q4 * 2;
            float4 k0 = kp[0], k1 = kp[1];
            float4 v0 = vp[0], v1 = vp[1];
            int d0 = q4 * 8;
            Kt[d0 + 0][k] = k0.x; Kt[d0 + 1][k] = k0.y; Kt[d0 + 2][k] = k0.z; Kt[d0 + 3][k] = k0.w;
            Kt[d0 + 4][k] = k1.x; Kt[d0 + 5][k] = k1.y; Kt[d0 + 6][k] = k1.z; Kt[d0 + 7][k] = k1.w;
            Vt[d0 + 0][k] = v0.x; Vt[d0 + 1][k] = v0.y; Vt[d0 + 2][k] = v0.z; Vt[d0 + 3][k] = v0.w;
            Vt[d0 + 4][k] = v1.x; Vt[d0 + 5][k] = v1.y; Vt[d0 + 6][k] = v1.z; Vt[d0 + 7][k] = v1.w;
        }
        float km = maskp[(size_t)b * Nn + n0 + lane];
        bool kok = (km != 0.0f);
        int tag = idxp[(size_t)b * Nn + n0 + lane];
        __syncthreads();

        // wave-level whole-chunk skip
        bool anyUse = __any(kok && (unsigned)(tag - m0) < 8u);
        float minm = fminf(fminf(fminf(mrun[0], mrun[1]), fminf(mrun[2], mrun[3])),
                           fminf(fminf(mrun[4], mrun[5]), fminf(mrun[6], mrun[7])));
        if (!anyUse && minm > -5e9f) continue;

        float kreg[32], vreg[32];
#pragma unroll
        for (int j = 0; j < 32; ++j) kreg[j] = Kt[j][lane];
#pragma unroll
        for (int j = 0; j < 32; ++j) vreg[j] = Vt[dv][kh * 32 + j];

#pragma unroll
        for (int qi = 0; qi < 8; ++qi) {
            bool ok = kok && (tag == m0 + qi);
            if (!__any(ok) && mrun[qi] > -5e9f) continue;

            const float4* qrow = (const float4*)&Qs[wid * 8 + qi][0];
            float s0 = 0.f, s1 = 0.f, s2 = 0.f, s3 = 0.f;
#pragma unroll
            for (int j4 = 0; j4 < 8; ++j4) {
                float4 qv = qrow[j4];
                s0 += qv.x * kreg[j4 * 4 + 0];
                s1 += qv.y * kreg[j4 * 4 + 1];
                s2 += qv.z * kreg[j4 * 4 + 2];
                s3 += qv.w * kreg[j4 * 4 + 3];
            }
            float s = (s0 + s1) + (s2 + s3);
            s = ok ? s * SCALE_INV_SQRT_D : -1e10f;

            float cmax = s;
#pragma unroll
            for (int off = 32; off >= 1; off >>= 1)
                cmax = fmaxf(cmax, __shfl_xor(cmax, off, 64));

            if (cmax > mrun[qi]) {
                float corr = __expf(mrun[qi] - cmax);
                lpart[qi] *= corr;
                acc[qi] *= corr;
                mrun[qi] = cmax;
            }
            float p = __expf(s - mrun[qi]);
            lpart[qi] += p;
            Ps[wid][lane] = p;

            float a = acc[qi];
#pragma unroll
            for (int j4 = 0; j4 < 8; ++j4) {
                float4 pv = *(const float4*)&Ps[wid][kh * 32 + j4 * 4];
                a += pv.x * vreg[j4 * 4 + 0];
                a += pv.y * vreg[j4 * 4 + 1];
                a += pv.z * vreg[j4 * 4 + 2];
                a += pv.w * vreg[j4 * 4 + 3];
            }
            acc[qi] = a;
        }
    }

#pragma unroll
    for (int qi = 0; qi < 8; ++qi) {
        float l = lpart[qi];
#pragma unroll
        for (int off = 32; off >= 1; off >>= 1) l += __shfl_xor(l, off, 64);
        float a = acc[qi] + __shfl_xor(acc[qi], 32, 64);
        float inv = 1.0f / l;
        if (lane < 32) {
            int r = wid * 8 + qi;
            float qd = Qs[r][lane];
            O[((size_t)b * M + mblk + r) * Dd + (size_t)h * DHh + lane] = qd + a * inv;
        }
    }
}

// ---------------------------------------------------------------------------
// Obs (nmask) flash attention, KVBLK=128: two keys per lane. Per-query
// overhead (Qs reads, butterfly max, exp/rescale) paid once per 128 keys.
// kreg[64]/vreg[64] filled once per chunk, reused across 8 queries.
// Kt/Vt stride 129: kreg fill bank=(j+lane)%32 (2-way, free); vreg fill
// bank=(dv+j)%32 (2-way, free). Branchless online softmax (validated r8).
// ---------------------------------------------------------------------------
__global__ __launch_bounds__(256, 2) void attn_obs_kernel(
    const float* __restrict__ Q, const float* __restrict__ Kp, const float* __restrict__ Vp,
    const float* __restrict__ maskp, float* __restrict__ O) {
    __shared__ float Kt[32][129];  // Kt[d][k], k = 0..127
    __shared__ float Vt[32][129];
    __shared__ float Qs[32][36];   // 32 queries x 32 dims
    __shared__ float Ps[4][128];   // per-wave softmax weights (128 keys)

    int b = blockIdx.z, h = blockIdx.y;
    int tid = threadIdx.x;
    int lane = tid & 63, wid = tid >> 6;
    int mblk = blockIdx.x * 32;
    int m0 = mblk + wid * 8;

    int kh = lane >> 5;   // AV: key half (within each 64-key group)
    int dv = lane & 31;   // AV: dim

    {
        int r = tid >> 3, c = tid & 7;
        float4 qv = *(const float4*)(Q + ((size_t)b * Nn + mblk + r) * Dd + (size_t)h * DHh + c * 4);
        *(float4*)&Qs[r][c * 4] = qv;
    }

    float acc[8], lpart[8], mrun[8];
    bool okq[8];
#pragma unroll
    for (int qi = 0; qi < 8; ++qi) {
        acc[qi] = 0.f; lpart[qi] = 0.f; mrun[qi] = -INFINITY;
        okq[qi] = (maskp[(size_t)b * Nn + m0 + qi] != 0.0f);
    }

    for (int n0 = 0; n0 < Nn; n0 += 128) {
        __syncthreads();
        {   // stage K/V transposed: thread -> key k = tid>>1, dim-half hf = tid&1
            int k = tid >> 1, hf = tid & 1;
            size_t gk = ((size_t)b * Nn + n0 + k) * Dd + (size_t)h * DHh + hf * 16;
            const float4* kp = (const float4*)(Kp + gk);
            const float4* vp = (const float4*)(Vp + gk);
#pragma unroll
            for (int q4 = 0; q4 < 4; ++q4) {
                float4 kv = kp[q4];
                float4 vv = vp[q4];
                int d0 = hf * 16 + q4 * 4;
                Kt[d0 + 0][k] = kv.x; Kt[d0 + 1][k] = kv.y;
                Kt[d0 + 2][k] = kv.z; Kt[d0 + 3][k] = kv.w;
                Vt[d0 + 0][k] = vv.x; Vt[d0 + 1][k] = vv.y;
                Vt[d0 + 2][k] = vv.z; Vt[d0 + 3][k] = vv.w;
            }
        }
        bool kok_a = (maskp[(size_t)b * Nn + n0 + lane] != 0.0f);
        bool kok_b = (maskp[(size_t)b * Nn + n0 + 64 + lane] != 0.0f);
        __syncthreads();

        // fills reused across 8 queries
        float kreg[64], vreg[64];
#pragma unroll
        for (int j = 0; j < 32; ++j) {
            kreg[j] = Kt[j][lane];
            kreg[32 + j] = Kt[j][64 + lane];
        }
#pragma unroll
        for (int j = 0; j < 32; ++j) {
            vreg[j] = Vt[dv][kh * 32 + j];
            vreg[32 + j] = Vt[dv][64 + kh * 32 + j];
        }

#pragma unroll
        for (int qi = 0; qi < 8; ++qi) {
            // ---- S phase: lane owns keys (n0+lane) and (n0+64+lane) ----
            const float4* qrow = (const float4*)&Qs[wid * 8 + qi][0];
            float sa0 = 0.f, sa1 = 0.f, sa2 = 0.f, sa3 = 0.f;
            float sb0 = 0.f, sb1 = 0.f, sb2 = 0.f, sb3 = 0.f;
#pragma unroll
            for (int j4 = 0; j4 < 8; ++j4) {
                float4 qv = qrow[j4];  // uniform broadcast, once per 2 keys
                sa0 += qv.x * kreg[j4 * 4 + 0];
                sa1 += qv.y * kreg[j4 * 4 + 1];
                sa2 += qv.z * kreg[j4 * 4 + 2];
                sa3 += qv.w * kreg[j4 * 4 + 3];
                sb0 += qv.x * kreg[32 + j4 * 4 + 0];
                sb1 += qv.y * kreg[32 + j4 * 4 + 1];
                sb2 += qv.z * kreg[32 + j4 * 4 + 2];
                sb3 += qv.w * kreg[32 + j4 * 4 + 3];
            }
            float sa = (sa0 + sa1) + (sa2 + sa3);
            float sb = (sb0 + sb1) + (sb2 + sb3);
            sa = (okq[qi] && kok_a) ? sa * SCALE_INV_SQRT_D : -1e10f;
            sb = (okq[qi] && kok_b) ? sb * SCALE_INV_SQRT_D : -1e10f;

            // one butterfly max per 128 keys
            float cmax = fmaxf(sa, sb);
#pragma unroll
            for (int off = 32; off >= 1; off >>= 1)
                cmax = fmaxf(cmax, __shfl_xor(cmax, off, 64));

            // branchless online rescale (exp(-inf)=0 covers first chunk)
            float nm = fmaxf(mrun[qi], cmax);
            float corr = __expf(mrun[qi] - nm);
            mrun[qi] = nm;
            float pa = __expf(sa - nm);
            float pb = __expf(sb - nm);
            lpart[qi] = lpart[qi] * corr + pa + pb;
            acc[qi] *= corr;
            Ps[wid][lane] = pa;
            Ps[wid][64 + lane] = pb;

            // ---- AV phase: lane = (kh, dv); both 64-key groups ----
            float a = acc[qi];
#pragma unroll
            for (int j4 = 0; j4 < 8; ++j4) {
                float4 pv = *(const float4*)&Ps[wid][kh * 32 + j4 * 4];
                a += pv.x * vreg[j4 * 4 + 0];
                a += pv.y * vreg[j4 * 4 + 1];
                a += pv.z * vreg[j4 * 4 + 2];
                a += pv.w * vreg[j4 * 4 + 3];
            }
#pragma unroll
            for (int j4 = 0; j4 < 8; ++j4) {
                float4 pv = *(const float4*)&Ps[wid][64 + kh * 32 + j4 * 4];
                a += pv.x * vreg[32 + j4 * 4 + 0];
                a += pv.y * vreg[32 + j4 * 4 + 1];
                a += pv.z * vreg[32 + j4 * 4 + 2];
                a += pv.w * vreg[32 + j4 * 4 + 3];
            }
            acc[qi] = a;
        }
    }

    // epilogue
#pragma unroll
    for (int qi = 0; qi < 8; ++qi) {
        float l = lpart[qi];
#pragma unroll
        for (int off = 32; off >= 1; off >>= 1) l += __shfl_xor(l, off, 64);
        float a = acc[qi] + __shfl_xor(acc[qi], 32, 64);
        float inv = 1.0f / l;
        if (lane < 32) {
            int r = wid * 8 + qi;
            float qd = Qs[r][lane];
            O[((size_t)b * Nn + mblk + r) * Dd + (size_t)h * DHh + lane] = qd + a * inv;
        }
    }
}

// ---------------------------------------------------------------------------
// IAA (hyperedge2hyperedge): tiny single-head attention over E=32.
// ---------------------------------------------------------------------------
__global__ void iaa_scores_kernel(const float* __restrict__ q, const float* __restrict__ k,
                                  float* __restrict__ s) {
    int t = blockIdx.x * 256 + threadIdx.x;
    if (t >= Bb * Ee * Ee) return;
    int j = t & (Ee - 1);
    int i = (t >> 5) & (Ee - 1);
    int b = t >> 10;
    const float4* qp = (const float4*)(q + ((size_t)b * Ee + i) * Dd);
    const float4* kp = (const float4*)(k + ((size_t)b * Ee + j) * Dd);
    float acc = 0.0f;
#pragma unroll
    for (int d = 0; d < 32; ++d) {
        float4 a = qp[d], c = kp[d];
        acc += a.x * c.x + a.y * c.y + a.z * c.z + a.w * c.w;
    }
    s[t] = acc * SCALE_INV_SQRT_D;
}

__global__ void iaa_softmax_kernel(float* __restrict__ s) {
    int r = blockIdx.x * 256 + threadIdx.x;
    if (r >= Bb * Ee) return;
    float* row = s + (size_t)r * Ee;
    float mx = -INFINITY;
    for (int j = 0; j < Ee; ++j) mx = fmaxf(mx, row[j]);
    float sum = 0.0f;
    for (int j = 0; j < Ee; ++j) sum += __expf(row[j] - mx);
    float inv = 1.0f / sum;
    for (int j = 0; j < Ee; ++j) row[j] = __expf(row[j] - mx) * inv;
}

__global__ void iaa_av_kernel(const float* __restrict__ s, const float* __restrict__ v,
                              float* __restrict__ o) {
    int t = blockIdx.x * 256 + threadIdx.x;
    if (t >= Bb * Ee * Dd) return;
    int d = t & (Dd - 1);
    int i = (t >> 7) & (Ee - 1);
    int b = t >> 12;
    const float* sr = s + ((size_t)b * Ee + i) * Ee;
    float acc = 0.0f;
#pragma unroll
    for (int j = 0; j < Ee; ++j) acc += sr[j] * v[((size_t)b * Ee + j) * Dd + d];
    o[t] = acc;
}

// ---------------------------------------------------------------------------
// Host-side orchestration
// ---------------------------------------------------------------------------
static inline void launch_gemm(hipStream_t st, const float* X0, const int* I0, int R0,
                               const float* X1, const int* I1, int R1, const float* X2,
                               const int* I2, int R2, const float* W, const float* bias,
                               const float* resid, float* C, int M, int K, int epi) {
    dim3 g((M + 31) / 32, 1, Bb);
    gemm_kernel<<<g, 256, 0, st>>>(X0, I0, R0, X1, I1, R1, X2, I2, R2, W, bias, resid, C, M, K,
                                   epi);
}

static inline void launch_attn_inc(hipStream_t st, const float* Q, const float* K, const float* V,
                                   const int* idxp, const float* maskp, float* O, int M) {
    dim3 g(M / 32, Hh, Bb);
    attn_inc_kernel<<<g, 256, 0, st>>>(Q, K, V, idxp, maskp, O, M);
}

static inline void launch_attn_obs(hipStream_t st, const float* Q, const float* K, const float* V,
                                   const float* maskp, float* O) {
    dim3 g(Nn / 32, Hh, Bb);
    attn_obs_kernel<<<g, 256, 0, st>>>(Q, K, V, maskp, O);
}

extern "C" void kernel_launch(void* const* d_in, const int* in_sizes, int n_in, void* d_out,
                              int out_size, void* d_ws, size_t ws_size, hipStream_t stream) {
    const float* x = (const float*)d_in[0];
    const float* mask = (const float*)d_in[1];
    const float* ymask = (const float*)d_in[2];
    const float* mark = (const float*)d_in[3];
    const float* w_obs = (const float*)d_in[4];
    const float* b_obs = (const float*)d_in[5];
    const float* w_tm = (const float*)d_in[6];
    const float* b_tm = (const float*)d_in[7];
    const float* var_w = (const float*)d_in[8];
    const float* tq_w = (const float*)d_in[9];
    const float* tq_b = (const float*)d_in[10];
    const float* tk_w = (const float*)d_in[11];
    const float* tk_b = (const float*)d_in[12];
    const float* tv_w = (const float*)d_in[13];
    const float* tv_b = (const float*)d_in[14];
    const float* to_w = (const float*)d_in[15];
    const float* to_b = (const float*)d_in[16];
    const float* vq_w = (const float*)d_in[17];
    const float* vq_b = (const float*)d_in[18];
    const float* vk_w = (const float*)d_in[19];
    const float* vk_b = (const float*)d_in[20];
    const float* vv_w = (const float*)d_in[21];
    const float* vv_b = (const float*)d_in[22];
    const float* vo_w = (const float*)d_in[23];
    const float* vo_b = (const float*)d_in[24];
    const float* sq_w = (const float*)d_in[25];
    const float* sq_b = (const float*)d_in[26];
    const float* sk_w = (const float*)d_in[27];
    const float* sk_b = (const float*)d_in[28];
    const float* sv_w = (const float*)d_in[29];
    const float* sv_b = (const float*)d_in[30];
    const float* so_w = (const float*)d_in[31];
    const float* so_b = (const float*)d_in[32];
    const float* iq_w = (const float*)d_in[33];
    const float* iq_b = (const float*)d_in[34];
    const float* ik_w = (const float*)d_in[35];
    const float* ik_b = (const float*)d_in[36];
    const float* iv_w = (const float*)d_in[37];
    const float* iv_b = (const float*)d_in[38];
    const int* vidx = (const int*)d_in[39];
    const int* tidx = (const int*)d_in[40];

    float* out = (float*)d_out;
    float* out_obs = out;
    float* out_temp = out + BND;
    float* out_var = out + BND + BLD;

    float* ws = (float*)d_ws;
    float* obs_a = ws;
    float* obs_b = obs_a + BND;
    float* qb = obs_b + BND;
    float* kb = qb + BND;
    float* vb = kb + BND;
    float* attno = vb + BND;
    float* temp_a = attno + BND;
    float* temp_b = temp_a + BLD;
    float* var_a = temp_b + BLD;
    float* var_b = var_a + BED;
    float* sbuf = var_b + BED;  // B*E*E

    enc_obs_kernel<<<(BND + 255) / 256, 256, 0, stream>>>(x, mask, ymask, w_obs, b_obs, obs_a);
    enc_temp_kernel<<<(BLD + 255) / 256, 256, 0, stream>>>(mark, w_tm, b_tm, temp_a);
    enc_var_kernel<<<(BED + 255) / 256, 256, 0, stream>>>(var_w, var_a);

    float* t_old = temp_a;
    float* v_old = var_a;
    float* o_old = obs_a;

    for (int i = 0; i < NLn; ++i) {
        int last = (i == NLn - 1);
        float* t_new = last ? out_temp : temp_b;
        float* v_new = (v_old == var_a) ? var_b : var_a;
        float* o_new = last ? out_obs : obs_b;

        const float* tqW = tq_w + (size_t)i * Dd * Dd;
        const float* tkW = tk_w + (size_t)i * 2 * Dd * Dd;
        const float* tvW = tv_w + (size_t)i * 2 * Dd * Dd;
        const float* toW = to_w + (size_t)i * Dd * Dd;
        const float* vqW = vq_w + (size_t)i * Dd * Dd;
        const float* vkW = vk_w + (size_t)i * 2 * Dd * Dd;
        const float* vvW = vv_w + (size_t)i * 2 * Dd * Dd;
        const float* voW = vo_w + (size_t)i * Dd * Dd;
        const float* sqW = sq_w + (size_t)i * Dd * Dd;
        const float* skW = sk_w + (size_t)i * 3 * Dd * Dd;
        const float* svW = sv_w + (size_t)i * 3 * Dd * Dd;
        const float* soW = so_w + (size_t)i * Dd * Dd;

        // ---- temporal MAB: Q=temp_he(old), K=[var_g(old), obs] ----
        launch_gemm(stream, t_old, nullptr, Ll, nullptr, nullptr, 0, nullptr, nullptr, 0, tqW,
                    tq_b + i * Dd, nullptr, qb, Ll, Dd, 0);
        launch_gemm(stream, v_old, vidx, Ee, o_old, nullptr, Nn, nullptr, nullptr, 0, tkW,
                    tk_b + i * Dd, nullptr, kb, Nn, 2 * Dd, 0);
        launch_gemm(stream, v_old, vidx, Ee, o_old, nullptr, Nn, nullptr, nullptr, 0, tvW,
                    tv_b + i * Dd, nullptr, vb, Nn, 2 * Dd, 0);
        launch_attn_inc(stream, qb, kb, vb, tidx, mask, attno, Ll);
        launch_gemm(stream, attno, nullptr, Ll, nullptr, nullptr, 0, nullptr, nullptr, 0, toW,
                    to_b + i * Dd, attno, t_new, Ll, Dd, 1);

        // ---- variable MAB: Q=var_he(old), K=[temp_g(old), obs] ----
        launch_gemm(stream, v_old, nullptr, Ee, nullptr, nullptr, 0, nullptr, nullptr, 0, vqW,
                    vq_b + i * Dd, nullptr, qb, Ee, Dd, 0);
        launch_gemm(stream, t_old, tidx, Ll, o_old, nullptr, Nn, nullptr, nullptr, 0, vkW,
                    vk_b + i * Dd, nullptr, kb, Nn, 2 * Dd, 0);
        launch_gemm(stream, t_old, tidx, Ll, o_old, nullptr, Nn, nullptr, nullptr, 0, vvW,
                    vv_b + i * Dd, nullptr, vb, Nn, 2 * Dd, 0);
        launch_attn_inc(stream, qb, kb, vb, vidx, mask, attno, Ee);
        launch_gemm(stream, attno, nullptr, Ee, nullptr, nullptr, 0, nullptr, nullptr, 0, voW,
                    vo_b + i * Dd, attno, v_new, Ee, Dd, 1);

        // ---- obs MAB: Q=obs(old), K=[temp_g(new), var_g(new), obs(old)] ----
        launch_gemm(stream, o_old, nullptr, Nn, nullptr, nullptr, 0, nullptr, nullptr, 0, sqW,
                    sq_b + i * Dd, nullptr, qb, Nn, Dd, 0);
        launch_gemm(stream, t_new, tidx, Ll, v_new, vidx, Ee, o_old, nullptr, Nn, skW,
                    sk_b + i * Dd, nullptr, kb, Nn, 3 * Dd, 0);
        launch_gemm(stream, t_new, tidx, Ll, v_new, vidx, Ee, o_old, nullptr, Nn, svW,
                    sv_b + i * Dd, nullptr, vb, Nn, 3 * Dd, 0);
        launch_attn_obs(stream, qb, kb, vb, mask, attno);
        launch_gemm(stream, attno, nullptr, Nn, nullptr, nullptr, 0, nullptr, nullptr, 0, soW,
                    so_b + i * Dd, attno, o_new, Nn, Dd, 2);

        t_old = t_new;
        v_old = v_new;
        o_old = o_new;
    }

    // ---- IAA on var_he (last layer) ----
    launch_gemm(stream, v_old, nullptr, Ee, nullptr, nullptr, 0, nullptr, nullptr, 0, iq_w, iq_b,
                nullptr, qb, Ee, Dd, 0);
    launch_gemm(stream, v_old, nullptr, Ee, nullptr, nullptr, 0, nullptr, nullptr, 0, ik_w, ik_b,
                nullptr, kb, Ee, Dd, 0);
    launch_gemm(stream, v_old, nullptr, Ee, nullptr, nullptr, 0, nullptr, nullptr, 0, iv_w, iv_b,
                nullptr, vb, Ee, Dd, 0);
    iaa_scores_kernel<<<(Bb * Ee * Ee + 255) / 256, 256, 0, stream>>>(qb, kb, sbuf);
    iaa_softmax_kernel<<<(Bb * Ee + 255) / 256, 256, 0, stream>>>(sbuf);
    iaa_av_kernel<<<(Bb * Ee * Dd + 255) / 256, 256, 0, stream>>>(sbuf, vb, out_var);
}